// Round 1
// baseline (159.405 us; speedup 1.0000x reference)
//
#include <hip/hip_runtime.h>
#include <hip/hip_bf16.h>
#include <stdint.h>
#include <stddef.h>

#define NS 8192
#define NT 8192
#define DD 512
#define NSEC 6

typedef __attribute__((ext_vector_type(8))) short short8;
typedef __attribute__((ext_vector_type(4))) float f32x4;

// ---- workspace layout (bytes) ----
#define WS_A    ((size_t)0)                         // NS*DD bf16  (source)
#define WS_B    (WS_A + (size_t)NS * DD * 2)        // NT*DD bf16  (target)
#define WS_SQS  (WS_B + (size_t)NT * DD * 2)        // NS f32 row sumsq (raw, un-normalized)
#define WS_SQT  (WS_SQS + (size_t)NS * 4)           // NT f32
#define WS_TSUM (WS_SQT + (size_t)NT * 4)           // NSEC*DD f32 per-section target sums
#define WS_CNT  (WS_TSUM + (size_t)NSEC * DD * 4)   // 8 f32 (count per section, as float)
#define WS_SSQ  (WS_CNT + 32)                       // 8 f32 (sum of sq_t per section)
#define WS_END  (WS_SSQ + 32)

__device__ __forceinline__ void gload16(const void* g, void* l) {
  __builtin_amdgcn_global_load_lds(
      (const __attribute__((address_space(1))) unsigned int*)g,
      (__attribute__((address_space(3))) unsigned int*)l, 16, 0, 0);
}

// ============================================================================
// K0: convert fp32 -> bf16 into ws, compute row sum-of-squares, and (targets)
// per-section sums tsum[6][512], counts, sum-of-sq_t via LDS partials.
// grid = 256 blocks (128 source + 128 target), 64 rows/block, wave handles 16.
// ============================================================================
__global__ __launch_bounds__(256) void prep_kernel(
    const float* __restrict__ src, const float* __restrict__ tgt,
    const int* __restrict__ tsec, char* __restrict__ ws) {
  const int bx = blockIdx.x;
  const bool isTgt = bx >= 128;
  const float* in = isTgt ? tgt : src;
  __hip_bfloat16* outb = (__hip_bfloat16*)(ws + (isTgt ? WS_B : WS_A));
  float* sq = (float*)(ws + (isTgt ? WS_SQT : WS_SQS));
  const int rowBase = (isTgt ? bx - 128 : bx) * 64;

  const int tid = threadIdx.x;
  const int wid = tid >> 6, lane = tid & 63;

  // per-wave partials; layout [wave][sec][j][lane] -> element d = lane*8+j
  __shared__ float lts[4][NSEC][8][64];   // 48 KiB
  __shared__ float lcnt[4][NSEC], lssq[4][NSEC];

  if (isTgt) {
    float* p = &lts[0][0][0][0];
    for (int i = tid; i < 4 * NSEC * 512; i += 256) p[i] = 0.f;
    if (tid < 4 * NSEC) { (&lcnt[0][0])[tid] = 0.f; (&lssq[0][0])[tid] = 0.f; }
    __syncthreads();
  }

  for (int i = 0; i < 16; ++i) {
    const int row = rowBase + wid * 16 + i;
    const float4* rp = (const float4*)(in + (size_t)row * DD);
    float4 v0 = rp[lane * 2], v1 = rp[lane * 2 + 1];
    float x[8] = {v0.x, v0.y, v0.z, v0.w, v1.x, v1.y, v1.z, v1.w};
    float ss = 0.f;
#pragma unroll
    for (int j = 0; j < 8; ++j) ss += x[j] * x[j];

    union { short8 s; __hip_bfloat16 h[8]; } u;
#pragma unroll
    for (int j = 0; j < 8; ++j) u.h[j] = __float2bfloat16(x[j]);
    *(short8*)(outb + (size_t)row * DD + lane * 8) = u.s;

#pragma unroll
    for (int off = 32; off >= 1; off >>= 1) ss += __shfl_xor(ss, off, 64);

    if (isTgt) {
      const int sec = tsec[row];
#pragma unroll
      for (int j = 0; j < 8; ++j) lts[wid][sec][j][lane] += x[j];
      if (lane == 0) { lcnt[wid][sec] += 1.f; lssq[wid][sec] += ss; }
    }
    if (lane == 0) sq[row] = ss;
  }

  if (isTgt) {
    __syncthreads();
    float* tsum = (float*)(ws + WS_TSUM);
    float* cnt  = (float*)(ws + WS_CNT);
    float* ssq  = (float*)(ws + WS_SSQ);
    for (int idx = tid; idx < NSEC * 512; idx += 256) {
      const int c = idx >> 9, r = idx & 511, j = r >> 6, l = r & 63;
      float v = lts[0][c][j][l] + lts[1][c][j][l] + lts[2][c][j][l] + lts[3][c][j][l];
      atomicAdd(&tsum[c * 512 + l * 8 + j], v);
    }
    if (tid < NSEC) {
      atomicAdd(&cnt[tid], lcnt[0][tid] + lcnt[1][tid] + lcnt[2][tid] + lcnt[3][tid]);
      atomicAdd(&ssq[tid], lssq[0][tid] + lssq[1][tid] + lssq[2][tid] + lssq[3][tid]);
    }
  }
}

// ============================================================================
// K1: loss_s analytic: ls[s] = (cnt[c]*sqs[s] + ssq[c] - 2*<src_s, tsum[c]>)
//                              / (D*Nt),  c = ssec[s].  Also zeroes loss_c.
// wave per row, 4 rows/block, grid 2048.
// ============================================================================
__global__ __launch_bounds__(256) void ls_kernel(
    const float* __restrict__ src, const int* __restrict__ ssec,
    const char* __restrict__ ws, float* __restrict__ out) {
  const int tid = threadIdx.x, wid = tid >> 6, lane = tid & 63;
  const int row = blockIdx.x * 4 + wid;
  const float* tsum = (const float*)(ws + WS_TSUM);
  const float* cnt  = (const float*)(ws + WS_CNT);
  const float* ssq  = (const float*)(ws + WS_SSQ);
  const float* sqs  = (const float*)(ws + WS_SQS);

  const int c = ssec[row];
  const float4* rp = (const float4*)(src + (size_t)row * DD);
  const float4* tp = (const float4*)(tsum + c * DD);
  float4 a0 = rp[lane * 2], a1 = rp[lane * 2 + 1];
  float4 b0 = tp[lane * 2], b1 = tp[lane * 2 + 1];
  float dot = a0.x * b0.x + a0.y * b0.y + a0.z * b0.z + a0.w * b0.w +
              a1.x * b1.x + a1.y * b1.y + a1.z * b1.z + a1.w * b1.w;
#pragma unroll
  for (int off = 32; off >= 1; off >>= 1) dot += __shfl_xor(dot, off, 64);

  if (lane == 0) {
    const float ls = (cnt[c] * sqs[row] + ssq[c] - 2.f * dot) *
                     (1.0f / ((float)DD * (float)NT));
    out[row] = ls;
    out[NS + row] = 0.f;   // loss_c accumulator base (gram kernel atomics into it)
  }
}

// ============================================================================
// K2: bf16 MFMA gram GEMM (128x128 tile, BK=32, 4 waves, 16x16x32 frags)
// fused hinge epilogue: hinge active only when d2raw < margin^2 * D = 128.
// ============================================================================
__global__ __launch_bounds__(256) void gram_kernel(
    const char* __restrict__ ws, const int* __restrict__ ssec,
    const int* __restrict__ tsec, float* __restrict__ out) {
  const short* Abf = (const short*)(ws + WS_A);
  const short* Bbf = (const short*)(ws + WS_B);
  const float* sqs = (const float*)(ws + WS_SQS);
  const float* sqt = (const float*)(ws + WS_SQT);

  // XCD-aware swizzle: each XCD (lin&7) owns 8 tile-rows; consecutive ids on
  // one XCD share a tile-col group -> A panel L2-resident, B streamed once.
  const int lin = blockIdx.x;
  const int m_blk = (lin & 7) * 8 + ((lin >> 3) & 7);
  const int n_blk = lin >> 6;

  const int tid = threadIdx.x, wid = tid >> 6, lane = tid & 63;
  const int wr = wid >> 1, wc = wid & 1;     // 2x2 wave grid, 64x64 per wave
  const int h = lane >> 4, q = lane & 15;

  __shared__ __align__(16) short As[128 * 32];
  __shared__ __align__(16) short Bs[128 * 32];

  f32x4 zero4 = {0.f, 0.f, 0.f, 0.f};
  f32x4 acc[4][4];
#pragma unroll
  for (int mi = 0; mi < 4; ++mi)
#pragma unroll
    for (int ni = 0; ni < 4; ++ni) acc[mi][ni] = zero4;

  const int rowA = m_blk * 128, rowB = n_blk * 128;
  const int sRow = lane >> 2;         // 0..15
  const int sCol = (lane & 3) * 8;    // bf16 elements

  for (int kt = 0; kt < DD / 32; ++kt) {
    const int k0 = kt * 32;
#pragma unroll
    for (int i = 0; i < 2; ++i) {
      const int r0 = wid * 32 + i * 16;  // wave-uniform LDS base row
      gload16(Abf + ((size_t)(rowA + r0 + sRow) * DD + k0 + sCol), &As[r0 * 32]);
      gload16(Bbf + ((size_t)(rowB + r0 + sRow) * DD + k0 + sCol), &Bs[r0 * 32]);
    }
    __syncthreads();

    short8 a[4], b[4];
#pragma unroll
    for (int mi = 0; mi < 4; ++mi)
      a[mi] = *(const short8*)&As[(wr * 64 + mi * 16 + q) * 32 + h * 8];
#pragma unroll
    for (int ni = 0; ni < 4; ++ni)
      b[ni] = *(const short8*)&Bs[(wc * 64 + ni * 16 + q) * 32 + h * 8];
#pragma unroll
    for (int mi = 0; mi < 4; ++mi)
#pragma unroll
      for (int ni = 0; ni < 4; ++ni)
        acc[mi][ni] =
            __builtin_amdgcn_mfma_f32_16x16x32_bf16(a[mi], b[ni], acc[mi][ni], 0, 0, 0);
    __syncthreads();
  }

  // ---- epilogue: loss_c hinge, rarely active ----
  // C/D layout (m89): col = lane&15 (q), row = h*4 + reg j
  float sqrow[4][4], sqcol[4];
#pragma unroll
  for (int mi = 0; mi < 4; ++mi)
#pragma unroll
    for (int j = 0; j < 4; ++j)
      sqrow[mi][j] = sqs[rowA + wr * 64 + mi * 16 + h * 4 + j];
#pragma unroll
  for (int ni = 0; ni < 4; ++ni) sqcol[ni] = sqt[rowB + wc * 64 + ni * 16 + q];

  float lc[4][4];
#pragma unroll
  for (int mi = 0; mi < 4; ++mi)
#pragma unroll
    for (int j = 0; j < 4; ++j) lc[mi][j] = 0.f;

#pragma unroll
  for (int mi = 0; mi < 4; ++mi)
#pragma unroll
    for (int ni = 0; ni < 4; ++ni)
#pragma unroll
      for (int j = 0; j < 4; ++j) {
        const float g = acc[mi][ni][j];
        const float d2r = sqrow[mi][j] + sqcol[ni] - 2.f * g;
        if (d2r < 128.f) {  // margin^2 * D; hinge candidate (rare)
          const int sr = rowA + wr * 64 + mi * 16 + h * 4 + j;
          const int sc = rowB + wc * 64 + ni * 16 + q;
          if (ssec[sr] != tsec[sc]) {
            const float d2 = fmaxf(d2r, 0.f) * (1.f / (float)DD);
            const float hh = 0.5f - sqrtf(d2);
            lc[mi][j] += hh * hh;
          }
        }
      }

  // reduce over the 16 lanes sharing h (cols), then one atomic per lane
#pragma unroll
  for (int mi = 0; mi < 4; ++mi)
#pragma unroll
    for (int j = 0; j < 4; ++j) {
      float v = lc[mi][j];
      v += __shfl_xor(v, 1, 64);
      v += __shfl_xor(v, 2, 64);
      v += __shfl_xor(v, 4, 64);
      v += __shfl_xor(v, 8, 64);
      lc[mi][j] = v;
    }
  float v = 0.f;
#pragma unroll
  for (int mi = 0; mi < 4; ++mi)
#pragma unroll
    for (int j = 0; j < 4; ++j)
      if (q == mi * 4 + j) v = lc[mi][j];
  const int row = rowA + wr * 64 + (q >> 2) * 16 + h * 4 + (q & 3);
  if (v != 0.f) atomicAdd(&out[NS + row], v * (1.0f / (float)NT));
}

extern "C" void kernel_launch(void* const* d_in, const int* in_sizes, int n_in,
                              void* d_out, int out_size, void* d_ws, size_t ws_size,
                              hipStream_t stream) {
  const float* src = (const float*)d_in[0];
  const float* tgt = (const float*)d_in[1];
  const int* ssec = (const int*)d_in[2];
  const int* tsec = (const int*)d_in[3];
  float* out = (float*)d_out;
  char* ws = (char*)d_ws;

  // zero the accumulated ws region (tsum/cnt/ssq) every call
  hipMemsetAsync(ws + WS_TSUM, 0, (size_t)(WS_END - WS_TSUM), stream);

  prep_kernel<<<256, 256, 0, stream>>>(src, tgt, tsec, ws);
  ls_kernel<<<2048, 256, 0, stream>>>(src, ssec, ws, out);
  gram_kernel<<<4096, 256, 0, stream>>>(ws, ssec, tsec, out);
}

// Round 2
// 120.866 us; speedup vs baseline: 1.3189x; 1.3189x over previous
//
#include <hip/hip_runtime.h>
#include <hip/hip_bf16.h>
#include <stdint.h>
#include <stddef.h>

#define NS 8192
#define NT 8192
#define DD 512
#define NTILES 16            // K tiles of BK=32: 512/32
#define INV_DNT (1.0f / ((float)DD * (float)NT))   // 1/4194304
#define INV_NT  (1.0f / (float)NT)

typedef __attribute__((ext_vector_type(8))) short short8;
typedef __attribute__((ext_vector_type(4))) float f32x4;

// ---- workspace layout (bytes) ----
#define WS_A    ((size_t)0)                    // NS*DD bf16
#define WS_B    (WS_A + (size_t)NS * DD * 2)   // NT*DD bf16
#define WS_SQS  (WS_B + (size_t)NT * DD * 2)   // NS f32 raw row sumsq
#define WS_SQT  (WS_SQS + (size_t)NS * 4)      // NT f32

__device__ __forceinline__ void gload16(const void* g, void* l) {
  __builtin_amdgcn_global_load_lds(
      (const __attribute__((address_space(1))) unsigned int*)g,
      (__attribute__((address_space(3))) unsigned int*)l, 16, 0, 0);
}

#define WAITVM4 asm volatile("s_waitcnt vmcnt(4)" ::: "memory")
#define WAITVM0 asm volatile("s_waitcnt vmcnt(0)" ::: "memory")
#define BAR     __builtin_amdgcn_s_barrier()
#define SCHEDB  __builtin_amdgcn_sched_barrier(0)

// ============================================================================
// prep: pure streaming fp32->bf16 convert + raw row sum-of-squares.
// 1024 blocks x 256 thr = 4096 waves; 16384 rows -> 4 rows/wave.
// ============================================================================
__global__ __launch_bounds__(256) void prep_kernel(
    const float* __restrict__ src, const float* __restrict__ tgt,
    char* __restrict__ ws) {
  const int tid = threadIdx.x, wid = tid >> 6, lane = tid & 63;
  __hip_bfloat16* Ab = (__hip_bfloat16*)(ws + WS_A);
  __hip_bfloat16* Bb = (__hip_bfloat16*)(ws + WS_B);
  float* sqs = (float*)(ws + WS_SQS);
  float* sqt = (float*)(ws + WS_SQT);

#pragma unroll
  for (int it = 0; it < 4; ++it) {
    const int row = blockIdx.x * 4 + wid + it * 4096;   // 0..16383
    const bool isT = row >= NS;
    const int r = isT ? row - NS : row;
    const float* in = (isT ? tgt : src) + (size_t)r * DD;
    const float4* rp = (const float4*)in;
    float4 v0 = rp[lane * 2], v1 = rp[lane * 2 + 1];
    float x[8] = {v0.x, v0.y, v0.z, v0.w, v1.x, v1.y, v1.z, v1.w};
    float ss = 0.f;
#pragma unroll
    for (int j = 0; j < 8; ++j) ss += x[j] * x[j];
    union { short8 s; __hip_bfloat16 h[8]; } u;
#pragma unroll
    for (int j = 0; j < 8; ++j) u.h[j] = __float2bfloat16(x[j]);
    *(short8*)((isT ? Bb : Ab) + (size_t)r * DD + lane * 8) = u.s;
#pragma unroll
    for (int off = 32; off >= 1; off >>= 1) ss += __shfl_xor(ss, off, 64);
    if (lane == 0) (isT ? sqt : sqs)[r] = ss;
  }
}

// ============================================================================
// gram: 256x256 tile, BK=32, 8 waves (2M x 4N), 3-deep LDS pipeline with
// counted vmcnt (T3/T4), XOR bank-swizzle (T2), setprio (T5).
// Fused epilogue computes BOTH loss_s (sum d2 over same-sec) and loss_c
// (hinge, rarely active) from the accumulators.
// ============================================================================
__global__ __launch_bounds__(512, 2) void gram_kernel(
    const char* __restrict__ ws, const int* __restrict__ ssec,
    const int* __restrict__ tsec, float* __restrict__ out) {
  // 3 buffers x (A 256x32 + B 256x32) bf16 = 96 KiB
  __shared__ __align__(16) char As[3][16384];
  __shared__ __align__(16) char Bs[3][16384];

  const float* sqs = (const float*)(ws + WS_SQS);
  const float* sqt = (const float*)(ws + WS_SQT);

  const int lin = blockIdx.x;          // 1024 blocks, 32x32 tiles
  const int m_blk = lin & 31, n_blk = lin >> 5;
  const int rowA = m_blk * 256, rowB = n_blk * 256;

  const int tid = threadIdx.x, wid = tid >> 6, lane = tid & 63;
  const int wrM = wid >> 2, wcN = wid & 3;     // 2 x 4 wave grid
  const int q = lane & 15, h = lane >> 4;

  // ---- staging address precompute (inverse of read-side swizzle) ----
  // linear LDS byte off of this lane's 16B chunk (round 0): rows wid*16..+15
  const int o0 = wid * 1024 + (lane >> 2) * 64 + (lane & 3) * 16;
  const int row_l = (o0 >> 6) ^ ((o0 >> 8) & 1);       // logical source row
  const int bir = (o0 & 63) ^ ((row_l & 3) << 4);      // logical byte in row
  const char* Asrc0 = ws + WS_A + (size_t)(rowA + row_l) * (DD * 2) + bir;
  const char* Bsrc0 = ws + WS_B + (size_t)(rowB + row_l) * (DD * 2) + bir;
  const int dst0 = wid * 1024;                         // wave-uniform LDS base

#define STAGE(tb, buf)                                                        \
  {                                                                           \
    const char* a0 = Asrc0 + (tb) * 64;                                       \
    const char* b0 = Bsrc0 + (tb) * 64;                                       \
    gload16(a0,          &As[buf][dst0]);                                     \
    gload16(a0 + 131072, &As[buf][8192 + dst0]);                              \
    gload16(b0,          &Bs[buf][dst0]);                                     \
    gload16(b0 + 131072, &Bs[buf][8192 + dst0]);                              \
  }

  // ---- read-side swizzled fragment base offsets ----
  const int axor = (q & 7) << 4;
  const int aoffb = (((wrM * 128 + q) * 64 + h * 16) ^ axor);  // + mi*1024
  const int boffb = (((wcN * 64 + q) * 64 + h * 16) ^ axor);   // + ni*1024

  f32x4 acc[8][4];
#pragma unroll
  for (int mi = 0; mi < 8; ++mi)
#pragma unroll
    for (int ni = 0; ni < 4; ++ni) acc[mi][ni] = (f32x4){0.f, 0.f, 0.f, 0.f};

  // ---- prologue: stage tiles 0,1; wait tile 0 landed ----
  STAGE(0, 0)
  STAGE(1, 1)
  WAITVM4;
  BAR;
  SCHEDB;

#pragma unroll
  for (int t = 0; t < NTILES; ++t) {
    const int cur = t % 3;
    if (t + 2 < NTILES) STAGE(t + 2, (t + 2) % 3)

    short8 a[8], b[4];
#pragma unroll
    for (int mi = 0; mi < 8; ++mi)
      a[mi] = *(const short8*)(&As[cur][0] + aoffb + mi * 1024);
#pragma unroll
    for (int ni = 0; ni < 4; ++ni)
      b[ni] = *(const short8*)(&Bs[cur][0] + boffb + ni * 1024);

    __builtin_amdgcn_s_setprio(1);
#pragma unroll
    for (int mi = 0; mi < 8; ++mi)
#pragma unroll
      for (int ni = 0; ni < 4; ++ni)
        acc[mi][ni] =
            __builtin_amdgcn_mfma_f32_16x16x32_bf16(a[mi], b[ni], acc[mi][ni], 0, 0, 0);
    __builtin_amdgcn_s_setprio(0);

    if (t + 2 < NTILES) {
      WAITVM4;   // tile t+1 fully landed (t+2's 4 loads may stay in flight)
      BAR;
      SCHEDB;
    } else if (t == NTILES - 2) {
      WAITVM0;   // last tile's loads: drain
      BAR;
      SCHEDB;
    }
    // t == NTILES-1: fall through to epilogue
  }

  // ---- epilogue ----
  // C/D layout: col = q (target), row = h*4 + j (source)
  float sqc[4];
  int tc[4];
#pragma unroll
  for (int ni = 0; ni < 4; ++ni) {
    const int c = rowB + wcN * 64 + ni * 16 + q;
    sqc[ni] = sqt[c];
    tc[ni] = tsec[c];
  }
  const int rbase = rowA + wrM * 128;

  __syncthreads();                       // all tile reads done; reuse LDS
  float* lsr = (float*)&As[0][0];        // [8 waves][4 h][32 (mi*4+j)]

#pragma unroll
  for (int mi = 0; mi < 8; ++mi) {
    const int r0 = rbase + mi * 16 + h * 4;
    const float4 s4 = *(const float4*)&sqs[r0];
    const int4 c4 = *(const int4*)&ssec[r0];
    const float sq4[4] = {s4.x, s4.y, s4.z, s4.w};
    const int sc4[4] = {c4.x, c4.y, c4.z, c4.w};
    float l[4] = {0.f, 0.f, 0.f, 0.f};
#pragma unroll
    for (int ni = 0; ni < 4; ++ni) {
#pragma unroll
      for (int j = 0; j < 4; ++j) {
        const float g = acc[mi][ni][j];
        const float d2r = sq4[j] + sqc[ni] - 2.f * g;
        if (sc4[j] == tc[ni]) {
          l[j] += fmaxf(d2r, 0.f);
        } else if (d2r < 128.f) {        // margin^2 * D; hinge (rare)
          const float d = sqrtf(fmaxf(d2r, 0.f) * (1.f / (float)DD));
          const float hh = 0.5f - d;
          atomicAdd(&out[NS + r0 + j], hh * hh * INV_NT);
        }
      }
    }
    // reduce over the 16 q-lanes (same h), then lanes q<4 publish to LDS
#pragma unroll
    for (int j = 0; j < 4; ++j) {
      float v = l[j];
      v += __shfl_xor(v, 1, 64);
      v += __shfl_xor(v, 2, 64);
      v += __shfl_xor(v, 4, 64);
      v += __shfl_xor(v, 8, 64);
      l[j] = v;
    }
    if (q < 4) {
      const float sv = (q == 0) ? l[0] : (q == 1) ? l[1] : (q == 2) ? l[2] : l[3];
      lsr[(wid * 4 + h) * 32 + mi * 4 + q] = sv;
    }
  }
  __syncthreads();

  // cross-wave (wcN) reduction: 256 rows, one atomic each
  if (tid < 256) {
    const int wrM_r = tid >> 7, within = tid & 127;
    const int mi = within >> 4, h_r = (within >> 2) & 3, j_r = within & 3;
    const int idx = mi * 4 + j_r;
    float v = lsr[((wrM_r * 4 + 0) * 4 + h_r) * 32 + idx] +
              lsr[((wrM_r * 4 + 1) * 4 + h_r) * 32 + idx] +
              lsr[((wrM_r * 4 + 2) * 4 + h_r) * 32 + idx] +
              lsr[((wrM_r * 4 + 3) * 4 + h_r) * 32 + idx];
    atomicAdd(&out[rowA + tid], v * INV_DNT);
  }
#undef STAGE
}

extern "C" void kernel_launch(void* const* d_in, const int* in_sizes, int n_in,
                              void* d_out, int out_size, void* d_ws, size_t ws_size,
                              hipStream_t stream) {
  const float* src = (const float*)d_in[0];
  const float* tgt = (const float*)d_in[1];
  const int* ssec = (const int*)d_in[2];
  const int* tsec = (const int*)d_in[3];
  float* out = (float*)d_out;
  char* ws = (char*)d_ws;

  hipMemsetAsync(out, 0, (size_t)2 * NS * sizeof(float), stream);
  prep_kernel<<<1024, 256, 0, stream>>>(src, tgt, ws);
  gram_kernel<<<1024, 512, 0, stream>>>(ws, ssec, tsec, out);
}